// Round 1
// baseline (3196.172 us; speedup 1.0000x reference)
//
#include <hip/hip_runtime.h>

#define N_NODES 100000
#define E_EDGES 1600000
#define D 128
#define AP 132  // padded LDS pitch (keeps 16B alignment, breaks bank aliasing)

// ---------------- Stage 1: edge scatter  h[dst] += e_attn * x[src] -------------
__global__ __launch_bounds__(256) void scatter_kernel(
    const float* __restrict__ x, const int* __restrict__ src,
    const int* __restrict__ dst, const float* __restrict__ ea,
    float* __restrict__ h, int E) {
    int idx = blockIdx.x * 256 + threadIdx.x;
    int e = idx >> 5;    // 32 lanes per edge, each handles a float4 (128 dims)
    int lane = idx & 31;
    if (e >= E) return;
    int s = src[e];
    int d = dst[e];
    float a = ea[e];
    float4 v = ((const float4*)(x + (size_t)s * D))[lane];
    float* hp = h + (size_t)d * D + lane * 4;
    atomicAdd(hp + 0, a * v.x);
    atomicAdd(hp + 1, a * v.y);
    atomicAdd(hp + 2, a * v.z);
    atomicAdd(hp + 3, a * v.w);
}

__device__ __forceinline__ float lrelu(float v) {
    return v >= 0.0f ? v : 0.01f * v;
}

// ------- Stage 2: out = LR((x+h)W1^T + b1) + LR((x*h)W2^T + b2) ---------------
// Block: 256 threads, tile = 32 nodes x 128 outputs, thread = 4 nodes x 4 outs.
__global__ __launch_bounds__(256) void gemm_kernel(
    const float* __restrict__ x, const float* __restrict__ h,
    const float* __restrict__ W1, const float* __restrict__ b1,
    const float* __restrict__ W2, const float* __restrict__ b2,
    float* __restrict__ out) {
    __shared__ float Aadd[32 * AP];
    __shared__ float Amul[32 * AP];

    const int n0 = blockIdx.x * 32;
    const int t = threadIdx.x;

    // Load 32 nodes x 128 dims of x and h; build (x+h) and (x*h) tiles in LDS.
    // 1024 float4s total -> 4 per thread.
#pragma unroll
    for (int i = 0; i < 4; ++i) {
        int fi = t + i * 256;      // float4 slot 0..1023
        int row = fi >> 5;         // 32 float4 per row
        int c4 = fi & 31;
        float4 xv = ((const float4*)(x + (size_t)(n0 + row) * D))[c4];
        float4 hv = ((const float4*)(h + (size_t)(n0 + row) * D))[c4];
        float4 av = make_float4(xv.x + hv.x, xv.y + hv.y, xv.z + hv.z, xv.w + hv.w);
        float4 mv = make_float4(xv.x * hv.x, xv.y * hv.y, xv.z * hv.z, xv.w * hv.w);
        *((float4*)&Aadd[row * AP + c4 * 4]) = av;
        *((float4*)&Amul[row * AP + c4 * 4]) = mv;
    }
    __syncthreads();

    const int m0 = (t >> 5) * 4;   // node sub-tile
    const int o0 = (t & 31) * 4;   // output sub-tile

    float acc1[4][4];
    float acc2[4][4];
#pragma unroll
    for (int i = 0; i < 4; ++i)
#pragma unroll
        for (int j = 0; j < 4; ++j) { acc1[i][j] = 0.0f; acc2[i][j] = 0.0f; }

#pragma unroll 4
    for (int d = 0; d < D; d += 4) {
        float4 a[4], m[4], w1[4], w2[4];
#pragma unroll
        for (int i = 0; i < 4; ++i) a[i] = *(const float4*)&Aadd[(m0 + i) * AP + d];
#pragma unroll
        for (int i = 0; i < 4; ++i) m[i] = *(const float4*)&Amul[(m0 + i) * AP + d];
#pragma unroll
        for (int j = 0; j < 4; ++j) w1[j] = *(const float4*)&W1[(size_t)(o0 + j) * D + d];
#pragma unroll
        for (int j = 0; j < 4; ++j) w2[j] = *(const float4*)&W2[(size_t)(o0 + j) * D + d];
#pragma unroll
        for (int i = 0; i < 4; ++i)
#pragma unroll
            for (int j = 0; j < 4; ++j) {
                acc1[i][j] += a[i].x * w1[j].x + a[i].y * w1[j].y
                            + a[i].z * w1[j].z + a[i].w * w1[j].w;
                acc2[i][j] += m[i].x * w2[j].x + m[i].y * w2[j].y
                            + m[i].z * w2[j].z + m[i].w * w2[j].w;
            }
    }

    // Epilogue: bias + LeakyReLU on both parts, then add; coalesced float4 store.
#pragma unroll
    for (int i = 0; i < 4; ++i) {
        float4 r;
        float v1, v2;
        v1 = lrelu(acc1[i][0] + b1[o0 + 0]); v2 = lrelu(acc2[i][0] + b2[o0 + 0]); r.x = v1 + v2;
        v1 = lrelu(acc1[i][1] + b1[o0 + 1]); v2 = lrelu(acc2[i][1] + b2[o0 + 1]); r.y = v1 + v2;
        v1 = lrelu(acc1[i][2] + b1[o0 + 2]); v2 = lrelu(acc2[i][2] + b2[o0 + 2]); r.z = v1 + v2;
        v1 = lrelu(acc1[i][3] + b1[o0 + 3]); v2 = lrelu(acc2[i][3] + b2[o0 + 3]); r.w = v1 + v2;
        ((float4*)(out + (size_t)(n0 + m0 + i) * D))[t & 31] = r;
    }
}

extern "C" void kernel_launch(void* const* d_in, const int* in_sizes, int n_in,
                              void* d_out, int out_size, void* d_ws, size_t ws_size,
                              hipStream_t stream) {
    const float* x  = (const float*)d_in[0];
    const int*   src = (const int*)d_in[1];
    const int*   dst = (const int*)d_in[2];
    const float* ea = (const float*)d_in[3];
    const float* W1 = (const float*)d_in[4];
    const float* b1 = (const float*)d_in[5];
    const float* W2 = (const float*)d_in[6];
    const float* b2 = (const float*)d_in[7];
    float* out = (float*)d_out;

    const size_t h_bytes = (size_t)N_NODES * D * sizeof(float);
    // Use workspace for h if it fits; otherwise alias d_out (safe: gemm block
    // reads its 32 h-rows into LDS before overwriting those same rows, and no
    // block reads another block's rows).
    float* h = (ws_size >= h_bytes) ? (float*)d_ws : out;

    hipMemsetAsync(h, 0, h_bytes, stream);

    {
        int total = E_EDGES * 32;
        int blocks = (total + 255) / 256;
        scatter_kernel<<<blocks, 256, 0, stream>>>(x, src, dst, ea, h, E_EDGES);
    }

    {
        int blocks = N_NODES / 32;  // 100000 % 32 == 0
        gemm_kernel<<<blocks, 256, 0, stream>>>(x, h, W1, b1, W2, b2, out);
    }
}

// Round 2
// 823.162 us; speedup vs baseline: 3.8828x; 3.8828x over previous
//
#include <hip/hip_runtime.h>

#define N_NODES 100000
#define E_EDGES 1600000
#define D 128
#define AP 132  // padded LDS pitch for gemm tiles

// ===================== CSR build (counting sort by dst) =======================

__global__ __launch_bounds__(256) void hist_kernel(
    const int* __restrict__ dst, int* __restrict__ cnt, int E) {
    int e = blockIdx.x * 256 + threadIdx.x;
    if (e < E) atomicAdd(&cnt[dst[e]], 1);
}

// Per-block exclusive scan of 256 elements + block sums (Hillis-Steele in LDS).
__global__ __launch_bounds__(256) void scanA_kernel(
    const int* __restrict__ cnt, int* __restrict__ excl,
    int* __restrict__ bsum, int n) {
    __shared__ int tmp[256];
    int gid = blockIdx.x * 256 + threadIdx.x;
    int v = (gid < n) ? cnt[gid] : 0;
    tmp[threadIdx.x] = v;
    __syncthreads();
    for (int ofs = 1; ofs < 256; ofs <<= 1) {
        int t = (threadIdx.x >= ofs) ? tmp[threadIdx.x - ofs] : 0;
        __syncthreads();
        tmp[threadIdx.x] += t;
        __syncthreads();
    }
    int incl = tmp[threadIdx.x];
    if (gid < n) excl[gid] = incl - v;
    if (threadIdx.x == 255) bsum[blockIdx.x] = incl;
}

// Single-block exclusive scan of the (<=512) block sums, in place.
__global__ __launch_bounds__(512) void scanB_kernel(int* __restrict__ bsum, int nb) {
    __shared__ int tmp[512];
    int v = (threadIdx.x < nb) ? bsum[threadIdx.x] : 0;
    tmp[threadIdx.x] = v;
    __syncthreads();
    for (int ofs = 1; ofs < 512; ofs <<= 1) {
        int t = (threadIdx.x >= ofs) ? tmp[threadIdx.x - ofs] : 0;
        __syncthreads();
        tmp[threadIdx.x] += t;
        __syncthreads();
    }
    if (threadIdx.x < nb) bsum[threadIdx.x] = tmp[threadIdx.x] - v;
}

__global__ __launch_bounds__(256) void scanC_kernel(
    const int* __restrict__ excl, const int* __restrict__ bsumExcl,
    int* __restrict__ off, int n, int E) {
    int gid = blockIdx.x * 256 + threadIdx.x;
    if (gid < n) off[gid] = excl[gid] + bsumExcl[gid >> 8];
    if (gid == 0) off[n] = E;
}

__global__ __launch_bounds__(256) void fill_kernel(
    const int* __restrict__ src, const int* __restrict__ dst,
    const float* __restrict__ ea, const int* __restrict__ off,
    int* __restrict__ cursor, int* __restrict__ csr_src,
    float* __restrict__ csr_ea, int E) {
    int e = blockIdx.x * 256 + threadIdx.x;
    if (e >= E) return;
    int d = dst[e];
    int pos = off[d] + atomicAdd(&cursor[d], 1);
    csr_src[pos] = src[e];
    csr_ea[pos] = ea[e];
}

// ============ Gather: one wave per dst node, register accumulation ============
__global__ __launch_bounds__(256) void gather_kernel(
    const float* __restrict__ x, const int* __restrict__ csr_src,
    const float* __restrict__ csr_ea, const int* __restrict__ off,
    float* __restrict__ h) {
    int node = blockIdx.x * 4 + (threadIdx.x >> 6);
    if (node >= N_NODES) return;
    int lane = threadIdx.x & 63;
    int beg = off[node];
    int end = off[node + 1];
    float2 acc0 = make_float2(0.f, 0.f);
    float2 acc1 = make_float2(0.f, 0.f);
    int e = beg;
    for (; e + 1 < end; e += 2) {   // unroll-2 for ILP across edge loads
        int s0 = csr_src[e];
        int s1 = csr_src[e + 1];
        float a0 = csr_ea[e];
        float a1 = csr_ea[e + 1];
        float2 v0 = ((const float2*)(x + (size_t)s0 * D))[lane];
        float2 v1 = ((const float2*)(x + (size_t)s1 * D))[lane];
        acc0.x += a0 * v0.x; acc0.y += a0 * v0.y;
        acc1.x += a1 * v1.x; acc1.y += a1 * v1.y;
    }
    if (e < end) {
        int s0 = csr_src[e];
        float a0 = csr_ea[e];
        float2 v0 = ((const float2*)(x + (size_t)s0 * D))[lane];
        acc0.x += a0 * v0.x; acc0.y += a0 * v0.y;
    }
    acc0.x += acc1.x; acc0.y += acc1.y;
    ((float2*)(h + (size_t)node * D))[lane] = acc0;
}

// ================== Fallback: original atomic scatter =========================
__global__ __launch_bounds__(256) void scatter_kernel(
    const float* __restrict__ x, const int* __restrict__ src,
    const int* __restrict__ dst, const float* __restrict__ ea,
    float* __restrict__ h, int E) {
    int idx = blockIdx.x * 256 + threadIdx.x;
    int e = idx >> 5;
    int lane = idx & 31;
    if (e >= E) return;
    int s = src[e];
    int d = dst[e];
    float a = ea[e];
    float4 v = ((const float4*)(x + (size_t)s * D))[lane];
    float* hp = h + (size_t)d * D + lane * 4;
    atomicAdd(hp + 0, a * v.x);
    atomicAdd(hp + 1, a * v.y);
    atomicAdd(hp + 2, a * v.z);
    atomicAdd(hp + 3, a * v.w);
}

__device__ __forceinline__ float lrelu(float v) {
    return v >= 0.0f ? v : 0.01f * v;
}

// ------- GEMM: out = LR((x+h)W1^T + b1) + LR((x*h)W2^T + b2) ------------------
__global__ __launch_bounds__(256) void gemm_kernel(
    const float* __restrict__ x, const float* __restrict__ h,
    const float* __restrict__ W1, const float* __restrict__ b1,
    const float* __restrict__ W2, const float* __restrict__ b2,
    float* __restrict__ out) {
    __shared__ float Aadd[32 * AP];
    __shared__ float Amul[32 * AP];

    const int n0 = blockIdx.x * 32;
    const int t = threadIdx.x;

#pragma unroll
    for (int i = 0; i < 4; ++i) {
        int fi = t + i * 256;
        int row = fi >> 5;
        int c4 = fi & 31;
        float4 xv = ((const float4*)(x + (size_t)(n0 + row) * D))[c4];
        float4 hv = ((const float4*)(h + (size_t)(n0 + row) * D))[c4];
        float4 av = make_float4(xv.x + hv.x, xv.y + hv.y, xv.z + hv.z, xv.w + hv.w);
        float4 mv = make_float4(xv.x * hv.x, xv.y * hv.y, xv.z * hv.z, xv.w * hv.w);
        *((float4*)&Aadd[row * AP + c4 * 4]) = av;
        *((float4*)&Amul[row * AP + c4 * 4]) = mv;
    }
    __syncthreads();

    const int m0 = (t >> 5) * 4;
    const int o0 = (t & 31) * 4;

    float acc1[4][4];
    float acc2[4][4];
#pragma unroll
    for (int i = 0; i < 4; ++i)
#pragma unroll
        for (int j = 0; j < 4; ++j) { acc1[i][j] = 0.0f; acc2[i][j] = 0.0f; }

#pragma unroll 4
    for (int d = 0; d < D; d += 4) {
        float4 a[4], m[4], w1[4], w2[4];
#pragma unroll
        for (int i = 0; i < 4; ++i) a[i] = *(const float4*)&Aadd[(m0 + i) * AP + d];
#pragma unroll
        for (int i = 0; i < 4; ++i) m[i] = *(const float4*)&Amul[(m0 + i) * AP + d];
#pragma unroll
        for (int j = 0; j < 4; ++j) w1[j] = *(const float4*)&W1[(size_t)(o0 + j) * D + d];
#pragma unroll
        for (int j = 0; j < 4; ++j) w2[j] = *(const float4*)&W2[(size_t)(o0 + j) * D + d];
#pragma unroll
        for (int i = 0; i < 4; ++i)
#pragma unroll
            for (int j = 0; j < 4; ++j) {
                acc1[i][j] += a[i].x * w1[j].x + a[i].y * w1[j].y
                            + a[i].z * w1[j].z + a[i].w * w1[j].w;
                acc2[i][j] += m[i].x * w2[j].x + m[i].y * w2[j].y
                            + m[i].z * w2[j].z + m[i].w * w2[j].w;
            }
    }

#pragma unroll
    for (int i = 0; i < 4; ++i) {
        float4 r;
        float v1, v2;
        v1 = lrelu(acc1[i][0] + b1[o0 + 0]); v2 = lrelu(acc2[i][0] + b2[o0 + 0]); r.x = v1 + v2;
        v1 = lrelu(acc1[i][1] + b1[o0 + 1]); v2 = lrelu(acc2[i][1] + b2[o0 + 1]); r.y = v1 + v2;
        v1 = lrelu(acc1[i][2] + b1[o0 + 2]); v2 = lrelu(acc2[i][2] + b2[o0 + 2]); r.z = v1 + v2;
        v1 = lrelu(acc1[i][3] + b1[o0 + 3]); v2 = lrelu(acc2[i][3] + b2[o0 + 3]); r.w = v1 + v2;
        ((float4*)(out + (size_t)(n0 + m0 + i) * D))[t & 31] = r;
    }
}

extern "C" void kernel_launch(void* const* d_in, const int* in_sizes, int n_in,
                              void* d_out, int out_size, void* d_ws, size_t ws_size,
                              hipStream_t stream) {
    const float* x   = (const float*)d_in[0];
    const int*   src = (const int*)d_in[1];
    const int*   dst = (const int*)d_in[2];
    const float* ea  = (const float*)d_in[3];
    const float* W1  = (const float*)d_in[4];
    const float* b1  = (const float*)d_in[5];
    const float* W2  = (const float*)d_in[6];
    const float* b2  = (const float*)d_in[7];
    float* out = (float*)d_out;

    // h aliases d_out: gather writes every row once; gemm block reads its 32
    // rows into LDS (then __syncthreads) before overwriting those same rows.
    float* h = out;

    // Workspace layout (all 256B-aligned offsets)
    const size_t SZ_CNT  = (size_t)N_NODES * sizeof(int);        // 400,000
    const size_t SZ_OFF  = (size_t)(N_NODES + 1) * sizeof(int);  // 400,004
    const size_t SZ_BSUM = 512 * sizeof(int);
    const size_t SZ_CSRI = (size_t)E_EDGES * sizeof(int);        // 6.4 MB
    auto align256 = [](size_t v) { return (v + 255) & ~(size_t)255; };
    size_t o_cnt  = 0;
    size_t o_off  = o_cnt + align256(SZ_CNT);
    size_t o_excl = o_off + align256(SZ_OFF);
    size_t o_bsum = o_excl + align256(SZ_CNT);
    size_t o_csrs = o_bsum + align256(SZ_BSUM);
    size_t o_csre = o_csrs + align256(SZ_CSRI);
    size_t need   = o_csre + align256(SZ_CSRI);

    const int NB_E = (E_EDGES + 255) / 256;          // 6250
    const int NB_N = (N_NODES + 255) / 256;          // 391

    if (ws_size >= need) {
        char* ws = (char*)d_ws;
        int*   cnt     = (int*)(ws + o_cnt);
        int*   off     = (int*)(ws + o_off);
        int*   excl    = (int*)(ws + o_excl);
        int*   bsum    = (int*)(ws + o_bsum);
        int*   csr_src = (int*)(ws + o_csrs);
        float* csr_ea  = (float*)(ws + o_csre);

        hipMemsetAsync(cnt, 0, SZ_CNT, stream);
        hist_kernel<<<NB_E, 256, 0, stream>>>(dst, cnt, E_EDGES);
        scanA_kernel<<<NB_N, 256, 0, stream>>>(cnt, excl, bsum, N_NODES);
        scanB_kernel<<<1, 512, 0, stream>>>(bsum, NB_N);
        scanC_kernel<<<NB_N, 256, 0, stream>>>(excl, bsum, off, N_NODES, E_EDGES);
        hipMemsetAsync(cnt, 0, SZ_CNT, stream);      // reuse as fill cursor
        fill_kernel<<<NB_E, 256, 0, stream>>>(src, dst, ea, off, cnt,
                                              csr_src, csr_ea, E_EDGES);
        gather_kernel<<<(N_NODES + 3) / 4, 256, 0, stream>>>(x, csr_src, csr_ea,
                                                             off, h);
    } else {
        // Fallback: atomic scatter (proven correct in R1)
        hipMemsetAsync(h, 0, (size_t)N_NODES * D * sizeof(float), stream);
        int total = E_EDGES * 32;
        scatter_kernel<<<(total + 255) / 256, 256, 0, stream>>>(x, src, dst, ea,
                                                                h, E_EDGES);
    }

    gemm_kernel<<<N_NODES / 32, 256, 0, stream>>>(x, h, W1, b1, W2, b2, out);
}

// Round 3
// 461.507 us; speedup vs baseline: 6.9255x; 1.7836x over previous
//
#include <hip/hip_runtime.h>

#define N_NODES 100000
#define E_EDGES 1600000
#define D 128
#define AP 132   // padded LDS pitch for fallback fp32 gemm
#define ASTR 136 // bf16 elements per LDS row in MFMA gemm (272 B; 2-way bank alias = free)

typedef short s16x8 __attribute__((ext_vector_type(8)));
typedef float f32x4 __attribute__((ext_vector_type(4)));

__device__ __forceinline__ unsigned short f2bf(float f) {
    union { float f; unsigned u; } v;
    v.f = f;
    unsigned r = v.u + 0x7FFFu + ((v.u >> 16) & 1u);  // RNE
    return (unsigned short)(r >> 16);
}

__device__ __forceinline__ float lrelu(float v) {
    return v >= 0.0f ? v : 0.01f * v;
}

// ===================== CSR build (counting sort by dst) =======================

__global__ __launch_bounds__(256) void hist_kernel(
    const int* __restrict__ dst, int* __restrict__ cnt, int E) {
    int e = blockIdx.x * 256 + threadIdx.x;
    if (e < E) atomicAdd(&cnt[dst[e]], 1);
}

__global__ __launch_bounds__(256) void scanA_kernel(
    const int* __restrict__ cnt, int* __restrict__ excl,
    int* __restrict__ bsum, int n) {
    __shared__ int tmp[256];
    int gid = blockIdx.x * 256 + threadIdx.x;
    int v = (gid < n) ? cnt[gid] : 0;
    tmp[threadIdx.x] = v;
    __syncthreads();
    for (int ofs = 1; ofs < 256; ofs <<= 1) {
        int t = (threadIdx.x >= ofs) ? tmp[threadIdx.x - ofs] : 0;
        __syncthreads();
        tmp[threadIdx.x] += t;
        __syncthreads();
    }
    int incl = tmp[threadIdx.x];
    if (gid < n) excl[gid] = incl - v;
    if (threadIdx.x == 255) bsum[blockIdx.x] = incl;
}

__global__ __launch_bounds__(512) void scanB_kernel(int* __restrict__ bsum, int nb) {
    __shared__ int tmp[512];
    int v = (threadIdx.x < nb) ? bsum[threadIdx.x] : 0;
    tmp[threadIdx.x] = v;
    __syncthreads();
    for (int ofs = 1; ofs < 512; ofs <<= 1) {
        int t = (threadIdx.x >= ofs) ? tmp[threadIdx.x - ofs] : 0;
        __syncthreads();
        tmp[threadIdx.x] += t;
        __syncthreads();
    }
    if (threadIdx.x < nb) bsum[threadIdx.x] = tmp[threadIdx.x] - v;
}

__global__ __launch_bounds__(256) void scanC_kernel(
    const int* __restrict__ excl, const int* __restrict__ bsumExcl,
    int* __restrict__ off, int n, int E) {
    int gid = blockIdx.x * 256 + threadIdx.x;
    if (gid < n) off[gid] = excl[gid] + bsumExcl[gid >> 8];
    if (gid == 0) off[n] = E;
}

__global__ __launch_bounds__(256) void fill_kernel(
    const int* __restrict__ src, const int* __restrict__ dst,
    const float* __restrict__ ea, const int* __restrict__ off,
    int* __restrict__ cursor, int* __restrict__ csr_src,
    float* __restrict__ csr_ea, int E) {
    int e = blockIdx.x * 256 + threadIdx.x;
    if (e >= E) return;
    int d = dst[e];
    int pos = off[d] + atomicAdd(&cursor[d], 1);
    csr_src[pos] = src[e];
    csr_ea[pos] = ea[e];
}

// ============ Gather: one wave per dst node, register accumulation ============
__global__ __launch_bounds__(256) void gather_kernel(
    const float* __restrict__ x, const int* __restrict__ csr_src,
    const float* __restrict__ csr_ea, const int* __restrict__ off,
    float* __restrict__ h) {
    int node = blockIdx.x * 4 + (threadIdx.x >> 6);
    if (node >= N_NODES) return;
    int lane = threadIdx.x & 63;
    int beg = off[node];
    int end = off[node + 1];
    float2 acc0 = make_float2(0.f, 0.f);
    float2 acc1 = make_float2(0.f, 0.f);
    int e = beg;
    for (; e + 1 < end; e += 2) {
        int s0 = csr_src[e];
        int s1 = csr_src[e + 1];
        float a0 = csr_ea[e];
        float a1 = csr_ea[e + 1];
        float2 v0 = ((const float2*)(x + (size_t)s0 * D))[lane];
        float2 v1 = ((const float2*)(x + (size_t)s1 * D))[lane];
        acc0.x += a0 * v0.x; acc0.y += a0 * v0.y;
        acc1.x += a1 * v1.x; acc1.y += a1 * v1.y;
    }
    if (e < end) {
        int s0 = csr_src[e];
        float a0 = csr_ea[e];
        float2 v0 = ((const float2*)(x + (size_t)s0 * D))[lane];
        acc0.x += a0 * v0.x; acc0.y += a0 * v0.y;
    }
    acc0.x += acc1.x; acc0.y += acc1.y;
    ((float2*)(h + (size_t)node * D))[lane] = acc0;
}

// ================== Fallback: atomic scatter ==================================
__global__ __launch_bounds__(256) void scatter_kernel(
    const float* __restrict__ x, const int* __restrict__ src,
    const int* __restrict__ dst, const float* __restrict__ ea,
    float* __restrict__ h, int E) {
    int idx = blockIdx.x * 256 + threadIdx.x;
    int e = idx >> 5;
    int lane = idx & 31;
    if (e >= E) return;
    int s = src[e];
    int d = dst[e];
    float a = ea[e];
    float4 v = ((const float4*)(x + (size_t)s * D))[lane];
    float* hp = h + (size_t)d * D + lane * 4;
    atomicAdd(hp + 0, a * v.x);
    atomicAdd(hp + 1, a * v.y);
    atomicAdd(hp + 2, a * v.z);
    atomicAdd(hp + 3, a * v.w);
}

// ============== W pre-swizzle into B-fragment order, fp32 -> bf16 =============
// Layout: Wswz[(((mat*4+ks)*8+ct)*64+lane)*8 + j] = W_mat[ct*16+(lane&15)]
//                                                       [ks*32+(lane>>4)*8+j]
__global__ __launch_bounds__(256) void wconv_kernel(
    const float* __restrict__ W1, const float* __restrict__ W2,
    unsigned short* __restrict__ Wswz) {
    int tid = blockIdx.x * 256 + threadIdx.x;  // 0..4095
    if (tid >= 2 * 4 * 8 * 64) return;
    int lane = tid & 63;
    int ct   = (tid >> 6) & 7;
    int ks   = (tid >> 9) & 3;
    int mat  = tid >> 11;
    const float* W = mat ? W2 : W1;
    int o  = ct * 16 + (lane & 15);
    int k0 = ks * 32 + (lane >> 4) * 8;
    const float* sp = W + (size_t)o * D + k0;
    unsigned short* dp = Wswz + (size_t)tid * 8;
    ushort4 lo, hi;
    lo.x = f2bf(sp[0]); lo.y = f2bf(sp[1]); lo.z = f2bf(sp[2]); lo.w = f2bf(sp[3]);
    hi.x = f2bf(sp[4]); hi.y = f2bf(sp[5]); hi.z = f2bf(sp[6]); hi.w = f2bf(sp[7]);
    *(ushort4*)(dp + 0) = lo;
    *(ushort4*)(dp + 4) = hi;
}

// ============== MFMA GEMM: out = LR((x+h)W1^T+b1) + LR((x*h)W2^T+b2) ==========
// Block: 256 thr = 4 waves, 64 nodes x 128 outs. Wave w owns ct tiles {w, w+4}
// with B frags persistent in registers (loaded once). A tiles (bf16) in LDS.
__global__ __launch_bounds__(256, 4) void mfma_gemm_kernel(
    const float* __restrict__ x, const float* __restrict__ h,
    const unsigned short* __restrict__ Wswz,
    const float* __restrict__ b1, const float* __restrict__ b2,
    float* __restrict__ out) {
    __shared__ unsigned short A[2][64 * ASTR];  // [part][row*ASTR + k], 34816 B

    const int n0 = blockIdx.x * 64;
    const int t = threadIdx.x;
    const int lane = t & 63;
    const int wv = t >> 6;

    // ---- Stage A tiles: (x+h) and (x*h) as bf16. 2048 float4 slots, 8/thread.
#pragma unroll
    for (int i = 0; i < 8; ++i) {
        int s = t + i * 256;
        int row = s >> 5;
        int c4 = s & 31;
        int srcrow = n0 + row;
        if (srcrow >= N_NODES) srcrow = N_NODES - 1;  // tail clamp (rows unused)
        float4 xv = ((const float4*)(x + (size_t)srcrow * D))[c4];
        float4 hv = ((const float4*)(h + (size_t)srcrow * D))[c4];
        ushort4 av, mv;
        av.x = f2bf(xv.x + hv.x); av.y = f2bf(xv.y + hv.y);
        av.z = f2bf(xv.z + hv.z); av.w = f2bf(xv.w + hv.w);
        mv.x = f2bf(xv.x * hv.x); mv.y = f2bf(xv.y * hv.y);
        mv.z = f2bf(xv.z * hv.z); mv.w = f2bf(xv.w * hv.w);
        *(ushort4*)&A[0][row * ASTR + c4 * 4] = av;
        *(ushort4*)&A[1][row * ASTR + c4 * 4] = mv;
    }

    // ---- Preload persistent B fragments (2 ct x 2 mats x 4 ks), coalesced.
    s16x8 Bf[2][2][4];
    float bb1[2], bb2[2];
#pragma unroll
    for (int ci = 0; ci < 2; ++ci) {
        int ct = wv + ci * 4;
        bb1[ci] = b1[ct * 16 + (lane & 15)];
        bb2[ci] = b2[ct * 16 + (lane & 15)];
#pragma unroll
        for (int mat = 0; mat < 2; ++mat)
#pragma unroll
            for (int ks = 0; ks < 4; ++ks)
                Bf[ci][mat][ks] = *(const s16x8*)(
                    Wswz + ((size_t)(((mat * 4 + ks) * 8 + ct) * 64 + lane)) * 8);
    }

    __syncthreads();

    const int quad = lane >> 4;
    const int kq = quad * 8;

#pragma unroll
    for (int mt = 0; mt < 4; ++mt) {
        f32x4 acc[2][2];  // [ctIdx][part]
#pragma unroll
        for (int ci = 0; ci < 2; ++ci)
#pragma unroll
            for (int p = 0; p < 2; ++p) acc[ci][p] = (f32x4){0.f, 0.f, 0.f, 0.f};

        const int arow = mt * 16 + (lane & 15);
#pragma unroll
        for (int ks = 0; ks < 4; ++ks) {
            s16x8 a0 = *(const s16x8*)&A[0][arow * ASTR + ks * 32 + kq];
            s16x8 a1 = *(const s16x8*)&A[1][arow * ASTR + ks * 32 + kq];
#pragma unroll
            for (int ci = 0; ci < 2; ++ci) {
                acc[ci][0] = __builtin_amdgcn_mfma_f32_16x16x32_bf16(
                    a0, Bf[ci][0][ks], acc[ci][0], 0, 0, 0);
                acc[ci][1] = __builtin_amdgcn_mfma_f32_16x16x32_bf16(
                    a1, Bf[ci][1][ks], acc[ci][1], 0, 0, 0);
            }
        }

        // Epilogue: C/D layout col=lane&15, row=quad*4+reg (m89-verified).
#pragma unroll
        for (int ci = 0; ci < 2; ++ci) {
            int oc = (wv + ci * 4) * 16 + (lane & 15);
#pragma unroll
            for (int r = 0; r < 4; ++r) {
                int node = n0 + mt * 16 + quad * 4 + r;
                if (node < N_NODES) {
                    float v = lrelu(acc[ci][0][r] + bb1[ci])
                            + lrelu(acc[ci][1][r] + bb2[ci]);
                    out[(size_t)node * D + oc] = v;
                }
            }
        }
    }
}

// ============== Fallback fp32 GEMM (R2-proven) ================================
__global__ __launch_bounds__(256) void gemm_kernel(
    const float* __restrict__ x, const float* __restrict__ h,
    const float* __restrict__ W1, const float* __restrict__ b1,
    const float* __restrict__ W2, const float* __restrict__ b2,
    float* __restrict__ out) {
    __shared__ float Aadd[32 * AP];
    __shared__ float Amul[32 * AP];
    const int n0 = blockIdx.x * 32;
    const int t = threadIdx.x;
#pragma unroll
    for (int i = 0; i < 4; ++i) {
        int fi = t + i * 256;
        int row = fi >> 5;
        int c4 = fi & 31;
        float4 xv = ((const float4*)(x + (size_t)(n0 + row) * D))[c4];
        float4 hv = ((const float4*)(h + (size_t)(n0 + row) * D))[c4];
        float4 av = make_float4(xv.x + hv.x, xv.y + hv.y, xv.z + hv.z, xv.w + hv.w);
        float4 mv = make_float4(xv.x * hv.x, xv.y * hv.y, xv.z * hv.z, xv.w * hv.w);
        *((float4*)&Aadd[row * AP + c4 * 4]) = av;
        *((float4*)&Amul[row * AP + c4 * 4]) = mv;
    }
    __syncthreads();
    const int m0 = (t >> 5) * 4;
    const int o0 = (t & 31) * 4;
    float acc1[4][4];
    float acc2[4][4];
#pragma unroll
    for (int i = 0; i < 4; ++i)
#pragma unroll
        for (int j = 0; j < 4; ++j) { acc1[i][j] = 0.0f; acc2[i][j] = 0.0f; }
#pragma unroll 4
    for (int d = 0; d < D; d += 4) {
        float4 a[4], m[4], w1[4], w2[4];
#pragma unroll
        for (int i = 0; i < 4; ++i) a[i] = *(const float4*)&Aadd[(m0 + i) * AP + d];
#pragma unroll
        for (int i = 0; i < 4; ++i) m[i] = *(const float4*)&Amul[(m0 + i) * AP + d];
#pragma unroll
        for (int j = 0; j < 4; ++j) w1[j] = *(const float4*)&W1[(size_t)(o0 + j) * D + d];
#pragma unroll
        for (int j = 0; j < 4; ++j) w2[j] = *(const float4*)&W2[(size_t)(o0 + j) * D + d];
#pragma unroll
        for (int i = 0; i < 4; ++i)
#pragma unroll
            for (int j = 0; j < 4; ++j) {
                acc1[i][j] += a[i].x * w1[j].x + a[i].y * w1[j].y
                            + a[i].z * w1[j].z + a[i].w * w1[j].w;
                acc2[i][j] += m[i].x * w2[j].x + m[i].y * w2[j].y
                            + m[i].z * w2[j].z + m[i].w * w2[j].w;
            }
    }
#pragma unroll
    for (int i = 0; i < 4; ++i) {
        float4 r;
        float v1, v2;
        v1 = lrelu(acc1[i][0] + b1[o0 + 0]); v2 = lrelu(acc2[i][0] + b2[o0 + 0]); r.x = v1 + v2;
        v1 = lrelu(acc1[i][1] + b1[o0 + 1]); v2 = lrelu(acc2[i][1] + b2[o0 + 1]); r.y = v1 + v2;
        v1 = lrelu(acc1[i][2] + b1[o0 + 2]); v2 = lrelu(acc2[i][2] + b2[o0 + 2]); r.z = v1 + v2;
        v1 = lrelu(acc1[i][3] + b1[o0 + 3]); v2 = lrelu(acc2[i][3] + b2[o0 + 3]); r.w = v1 + v2;
        ((float4*)(out + (size_t)(n0 + m0 + i) * D))[t & 31] = r;
    }
}

extern "C" void kernel_launch(void* const* d_in, const int* in_sizes, int n_in,
                              void* d_out, int out_size, void* d_ws, size_t ws_size,
                              hipStream_t stream) {
    const float* x   = (const float*)d_in[0];
    const int*   src = (const int*)d_in[1];
    const int*   dst = (const int*)d_in[2];
    const float* ea  = (const float*)d_in[3];
    const float* W1  = (const float*)d_in[4];
    const float* b1  = (const float*)d_in[5];
    const float* W2  = (const float*)d_in[6];
    const float* b2  = (const float*)d_in[7];
    float* out = (float*)d_out;

    // h aliases d_out: gather writes every row once; gemm blocks read their own
    // rows (into LDS, then __syncthreads) before overwriting those same rows.
    float* h = out;

    const size_t SZ_WSWZ = 2 * 4 * 8 * 64 * 8 * sizeof(unsigned short);  // 64 KB
    const size_t SZ_CNT  = (size_t)N_NODES * sizeof(int);
    const size_t SZ_OFF  = (size_t)(N_NODES + 1) * sizeof(int);
    const size_t SZ_BSUM = 512 * sizeof(int);
    const size_t SZ_CSRI = (size_t)E_EDGES * sizeof(int);
    auto align256 = [](size_t v) { return (v + 255) & ~(size_t)255; };
    size_t o_wswz = 0;
    size_t o_cnt  = o_wswz + align256(SZ_WSWZ);
    size_t o_off  = o_cnt + align256(SZ_CNT);
    size_t o_excl = o_off + align256(SZ_OFF);
    size_t o_bsum = o_excl + align256(SZ_CNT);
    size_t o_csrs = o_bsum + align256(SZ_BSUM);
    size_t o_csre = o_csrs + align256(SZ_CSRI);
    size_t need_full = o_csre + align256(SZ_CSRI);

    const int NB_E = (E_EDGES + 255) / 256;
    const int NB_N = (N_NODES + 255) / 256;

    bool have_wswz = ws_size >= SZ_WSWZ;
    bool have_csr  = ws_size >= need_full;
    char* ws = (char*)d_ws;
    unsigned short* Wswz = (unsigned short*)(ws + o_wswz);

    if (have_csr) {
        int*   cnt     = (int*)(ws + o_cnt);
        int*   off     = (int*)(ws + o_off);
        int*   excl    = (int*)(ws + o_excl);
        int*   bsum    = (int*)(ws + o_bsum);
        int*   csr_src = (int*)(ws + o_csrs);
        float* csr_ea  = (float*)(ws + o_csre);

        hipMemsetAsync(cnt, 0, SZ_CNT, stream);
        hist_kernel<<<NB_E, 256, 0, stream>>>(dst, cnt, E_EDGES);
        scanA_kernel<<<NB_N, 256, 0, stream>>>(cnt, excl, bsum, N_NODES);
        scanB_kernel<<<1, 512, 0, stream>>>(bsum, NB_N);
        scanC_kernel<<<NB_N, 256, 0, stream>>>(excl, bsum, off, N_NODES, E_EDGES);
        hipMemsetAsync(cnt, 0, SZ_CNT, stream);
        fill_kernel<<<NB_E, 256, 0, stream>>>(src, dst, ea, off, cnt,
                                              csr_src, csr_ea, E_EDGES);
        gather_kernel<<<(N_NODES + 3) / 4, 256, 0, stream>>>(x, csr_src, csr_ea,
                                                             off, h);
    } else {
        hipMemsetAsync(h, 0, (size_t)N_NODES * D * sizeof(float), stream);
        int total = E_EDGES * 32;
        scatter_kernel<<<(total + 255) / 256, 256, 0, stream>>>(x, src, dst, ea,
                                                                h, E_EDGES);
    }

    if (have_wswz) {
        wconv_kernel<<<16, 256, 0, stream>>>(W1, W2, Wswz);
        int blocks = (N_NODES + 63) / 64;  // 1563, last block half-tail
        mfma_gemm_kernel<<<blocks, 256, 0, stream>>>(x, h, Wswz, b1, b2, out);
    } else {
        gemm_kernel<<<N_NODES / 32, 256, 0, stream>>>(x, h, W1, b1, W2, b2, out);
    }
}

// Round 4
// 331.757 us; speedup vs baseline: 9.6341x; 1.3911x over previous
//
#include <hip/hip_runtime.h>

#define N_NODES 100000
#define E_EDGES 1600000
#define D 128
#define AP 132   // padded LDS pitch for fallback fp32 gemm
#define ASTR 136 // bf16 elems per LDS row in MFMA gemm (272 B)

typedef short s16x8 __attribute__((ext_vector_type(8)));
typedef float f32x4 __attribute__((ext_vector_type(4)));

__device__ __forceinline__ unsigned short f2bf(float f) {
    union { float f; unsigned u; } v;
    v.f = f;
    unsigned r = v.u + 0x7FFFu + ((v.u >> 16) & 1u);  // RNE
    return (unsigned short)(r >> 16);
}

__device__ __forceinline__ float bf2f(unsigned short u) {
    union { unsigned u; float f; } v;
    v.u = ((unsigned)u) << 16;
    return v.f;
}

__device__ __forceinline__ float lrelu(float v) {
    return v >= 0.0f ? v : 0.01f * v;
}

// ==================== x -> bf16 table =========================================
__global__ __launch_bounds__(256) void xconv_kernel(
    const float* __restrict__ x, unsigned short* __restrict__ xbf) {
    int idx = blockIdx.x * 256 + threadIdx.x;           // 1.6M threads, 8 elems each
    const float4* xp = (const float4*)(x) + (size_t)idx * 2;
    float4 a = xp[0], b = xp[1];
    ushort4 lo, hi;
    lo.x = f2bf(a.x); lo.y = f2bf(a.y); lo.z = f2bf(a.z); lo.w = f2bf(a.w);
    hi.x = f2bf(b.x); hi.y = f2bf(b.y); hi.z = f2bf(b.z); hi.w = f2bf(b.w);
    ushort4* dp = (ushort4*)(xbf) + (size_t)idx * 2;
    dp[0] = lo; dp[1] = hi;
}

// ===================== CSR build (counting sort by dst) =======================

// hist + rank in one pass: rank[e] = running count of dst[e]
__global__ __launch_bounds__(256) void hist_kernel(
    const int* __restrict__ dst, int* __restrict__ cnt,
    int* __restrict__ rank, int E) {
    int e = blockIdx.x * 256 + threadIdx.x;
    if (e < E) rank[e] = atomicAdd(&cnt[dst[e]], 1);
}

__global__ __launch_bounds__(256) void scanA_kernel(
    const int* __restrict__ cnt, int* __restrict__ excl,
    int* __restrict__ bsum, int n) {
    __shared__ int tmp[256];
    int gid = blockIdx.x * 256 + threadIdx.x;
    int v = (gid < n) ? cnt[gid] : 0;
    tmp[threadIdx.x] = v;
    __syncthreads();
    for (int ofs = 1; ofs < 256; ofs <<= 1) {
        int t = (threadIdx.x >= ofs) ? tmp[threadIdx.x - ofs] : 0;
        __syncthreads();
        tmp[threadIdx.x] += t;
        __syncthreads();
    }
    int incl = tmp[threadIdx.x];
    if (gid < n) excl[gid] = incl - v;
    if (threadIdx.x == 255) bsum[blockIdx.x] = incl;
}

__global__ __launch_bounds__(512) void scanB_kernel(int* __restrict__ bsum, int nb) {
    __shared__ int tmp[512];
    int v = (threadIdx.x < nb) ? bsum[threadIdx.x] : 0;
    tmp[threadIdx.x] = v;
    __syncthreads();
    for (int ofs = 1; ofs < 512; ofs <<= 1) {
        int t = (threadIdx.x >= ofs) ? tmp[threadIdx.x - ofs] : 0;
        __syncthreads();
        tmp[threadIdx.x] += t;
        __syncthreads();
    }
    if (threadIdx.x < nb) bsum[threadIdx.x] = tmp[threadIdx.x] - v;
}

__global__ __launch_bounds__(256) void scanC_kernel(
    const int* __restrict__ excl, const int* __restrict__ bsumExcl,
    int* __restrict__ off, int n, int E) {
    int gid = blockIdx.x * 256 + threadIdx.x;
    if (gid < n) off[gid] = excl[gid] + bsumExcl[gid >> 8];
    if (gid == 0) off[n] = E;
}

// atomic-free fill: one packed 8B store per edge
__global__ __launch_bounds__(256) void fill_kernel(
    const int* __restrict__ src, const int* __restrict__ dst,
    const float* __restrict__ ea, const int* __restrict__ off,
    const int* __restrict__ rank, int2* __restrict__ csr, int E) {
    int e = blockIdx.x * 256 + threadIdx.x;
    if (e >= E) return;
    int d = dst[e];
    int pos = off[d] + rank[e];
    csr[pos] = make_int2(src[e], __float_as_int(ea[e]));
}

// ========== Gather (bf16 x): wave per node, half-wave per edge ================
__global__ __launch_bounds__(256) void gather_bf_kernel(
    const unsigned short* __restrict__ xbf, const int2* __restrict__ csr,
    const int* __restrict__ off, float* __restrict__ h) {
    int node = blockIdx.x * 4 + (threadIdx.x >> 6);
    int lane = threadIdx.x & 63;
    int half = lane >> 5;       // which edge of the pair
    int li = lane & 31;         // 4 dims per lane: li*4 .. li*4+3
    int beg = off[node];
    int nE = off[node + 1] - beg;

    float4 acc0 = make_float4(0.f, 0.f, 0.f, 0.f);
    float4 acc1 = make_float4(0.f, 0.f, 0.f, 0.f);
    int i = half;
    for (; i + 2 < nE; i += 4) {   // unroll-2 per half: edges i and i+2
        int2 p0 = csr[beg + i];
        int2 p1 = csr[beg + i + 2];
        float a0 = __int_as_float(p0.y);
        float a1 = __int_as_float(p1.y);
        ushort4 v0 = ((const ushort4*)(xbf + (size_t)p0.x * D))[li];
        ushort4 v1 = ((const ushort4*)(xbf + (size_t)p1.x * D))[li];
        acc0.x += a0 * bf2f(v0.x); acc0.y += a0 * bf2f(v0.y);
        acc0.z += a0 * bf2f(v0.z); acc0.w += a0 * bf2f(v0.w);
        acc1.x += a1 * bf2f(v1.x); acc1.y += a1 * bf2f(v1.y);
        acc1.z += a1 * bf2f(v1.z); acc1.w += a1 * bf2f(v1.w);
    }
    if (i < nE) {
        int2 p0 = csr[beg + i];
        float a0 = __int_as_float(p0.y);
        ushort4 v0 = ((const ushort4*)(xbf + (size_t)p0.x * D))[li];
        acc0.x += a0 * bf2f(v0.x); acc0.y += a0 * bf2f(v0.y);
        acc0.z += a0 * bf2f(v0.z); acc0.w += a0 * bf2f(v0.w);
    }
    acc0.x += acc1.x; acc0.y += acc1.y; acc0.z += acc1.z; acc0.w += acc1.w;
    // combine the two halves via cross-half shuffle
    float4 oth;
    oth.x = __shfl(acc0.x, lane ^ 32);
    oth.y = __shfl(acc0.y, lane ^ 32);
    oth.z = __shfl(acc0.z, lane ^ 32);
    oth.w = __shfl(acc0.w, lane ^ 32);
    acc0.x += oth.x; acc0.y += oth.y; acc0.z += oth.z; acc0.w += oth.w;
    if (half == 0)
        ((float4*)(h + (size_t)node * D))[li] = acc0;
}

// ========== Gather (fp32 x) — tier-1 fallback, packed csr =====================
__global__ __launch_bounds__(256) void gather_f32_kernel(
    const float* __restrict__ x, const int2* __restrict__ csr,
    const int* __restrict__ off, float* __restrict__ h) {
    int node = blockIdx.x * 4 + (threadIdx.x >> 6);
    int lane = threadIdx.x & 63;
    int beg = off[node];
    int end = off[node + 1];
    float2 acc0 = make_float2(0.f, 0.f);
    float2 acc1 = make_float2(0.f, 0.f);
    int e = beg;
    for (; e + 1 < end; e += 2) {
        int2 p0 = csr[e];
        int2 p1 = csr[e + 1];
        float a0 = __int_as_float(p0.y);
        float a1 = __int_as_float(p1.y);
        float2 v0 = ((const float2*)(x + (size_t)p0.x * D))[lane];
        float2 v1 = ((const float2*)(x + (size_t)p1.x * D))[lane];
        acc0.x += a0 * v0.x; acc0.y += a0 * v0.y;
        acc1.x += a1 * v1.x; acc1.y += a1 * v1.y;
    }
    if (e < end) {
        int2 p0 = csr[e];
        float a0 = __int_as_float(p0.y);
        float2 v0 = ((const float2*)(x + (size_t)p0.x * D))[lane];
        acc0.x += a0 * v0.x; acc0.y += a0 * v0.y;
    }
    acc0.x += acc1.x; acc0.y += acc1.y;
    ((float2*)(h + (size_t)node * D))[lane] = acc0;
}

// ================== Tier-0 fallback: atomic scatter ===========================
__global__ __launch_bounds__(256) void scatter_kernel(
    const float* __restrict__ x, const int* __restrict__ src,
    const int* __restrict__ dst, const float* __restrict__ ea,
    float* __restrict__ h, int E) {
    int idx = blockIdx.x * 256 + threadIdx.x;
    int e = idx >> 5;
    int lane = idx & 31;
    if (e >= E) return;
    int s = src[e];
    int d = dst[e];
    float a = ea[e];
    float4 v = ((const float4*)(x + (size_t)s * D))[lane];
    float* hp = h + (size_t)d * D + lane * 4;
    atomicAdd(hp + 0, a * v.x);
    atomicAdd(hp + 1, a * v.y);
    atomicAdd(hp + 2, a * v.z);
    atomicAdd(hp + 3, a * v.w);
}

// ============== W pre-swizzle into B-fragment order, fp32 -> bf16 =============
__global__ __launch_bounds__(256) void wconv_kernel(
    const float* __restrict__ W1, const float* __restrict__ W2,
    unsigned short* __restrict__ Wswz) {
    int tid = blockIdx.x * 256 + threadIdx.x;  // 0..4095
    if (tid >= 2 * 4 * 8 * 64) return;
    int lane = tid & 63;
    int ct   = (tid >> 6) & 7;
    int ks   = (tid >> 9) & 3;
    int mat  = tid >> 11;
    const float* W = mat ? W2 : W1;
    int o  = ct * 16 + (lane & 15);
    int k0 = ks * 32 + (lane >> 4) * 8;
    const float* sp = W + (size_t)o * D + k0;
    unsigned short* dp = Wswz + (size_t)tid * 8;
    ushort4 lo, hi;
    lo.x = f2bf(sp[0]); lo.y = f2bf(sp[1]); lo.z = f2bf(sp[2]); lo.w = f2bf(sp[3]);
    hi.x = f2bf(sp[4]); hi.y = f2bf(sp[5]); hi.z = f2bf(sp[6]); hi.w = f2bf(sp[7]);
    *(ushort4*)(dp + 0) = lo;
    *(ushort4*)(dp + 4) = hi;
}

// ============== MFMA GEMM: out = LR((x+h)W1^T+b1) + LR((x*h)W2^T+b2) ==========
template <bool XBF>
__global__ __launch_bounds__(256, 4) void mfma_gemm_kernel(
    const float* __restrict__ xf, const unsigned short* __restrict__ xb,
    const float* __restrict__ h, const unsigned short* __restrict__ Wswz,
    const float* __restrict__ b1, const float* __restrict__ b2,
    float* __restrict__ out) {
    __shared__ unsigned short A[2][64 * ASTR];

    const int n0 = blockIdx.x * 64;
    const int t = threadIdx.x;
    const int lane = t & 63;
    const int wv = t >> 6;

#pragma unroll
    for (int i = 0; i < 8; ++i) {
        int s = t + i * 256;
        int row = s >> 5;
        int c4 = s & 31;
        int srcrow = n0 + row;
        if (srcrow >= N_NODES) srcrow = N_NODES - 1;  // tail clamp (rows unused)
        float4 xv;
        if (XBF) {
            ushort4 xu = ((const ushort4*)(xb + (size_t)srcrow * D))[c4];
            xv = make_float4(bf2f(xu.x), bf2f(xu.y), bf2f(xu.z), bf2f(xu.w));
        } else {
            xv = ((const float4*)(xf + (size_t)srcrow * D))[c4];
        }
        float4 hv = ((const float4*)(h + (size_t)srcrow * D))[c4];
        ushort4 av, mv;
        av.x = f2bf(xv.x + hv.x); av.y = f2bf(xv.y + hv.y);
        av.z = f2bf(xv.z + hv.z); av.w = f2bf(xv.w + hv.w);
        mv.x = f2bf(xv.x * hv.x); mv.y = f2bf(xv.y * hv.y);
        mv.z = f2bf(xv.z * hv.z); mv.w = f2bf(xv.w * hv.w);
        *(ushort4*)&A[0][row * ASTR + c4 * 4] = av;
        *(ushort4*)&A[1][row * ASTR + c4 * 4] = mv;
    }

    s16x8 Bf[2][2][4];
    float bb1[2], bb2[2];
#pragma unroll
    for (int ci = 0; ci < 2; ++ci) {
        int ct = wv + ci * 4;
        bb1[ci] = b1[ct * 16 + (lane & 15)];
        bb2[ci] = b2[ct * 16 + (lane & 15)];
#pragma unroll
        for (int mat = 0; mat < 2; ++mat)
#pragma unroll
            for (int ks = 0; ks < 4; ++ks)
                Bf[ci][mat][ks] = *(const s16x8*)(
                    Wswz + ((size_t)(((mat * 4 + ks) * 8 + ct) * 64 + lane)) * 8);
    }

    __syncthreads();

    const int quad = lane >> 4;
    const int kq = quad * 8;

#pragma unroll
    for (int mt = 0; mt < 4; ++mt) {
        f32x4 acc[2][2];
#pragma unroll
        for (int ci = 0; ci < 2; ++ci)
#pragma unroll
            for (int p = 0; p < 2; ++p) acc[ci][p] = (f32x4){0.f, 0.f, 0.f, 0.f};

        const int arow = mt * 16 + (lane & 15);
#pragma unroll
        for (int ks = 0; ks < 4; ++ks) {
            s16x8 a0 = *(const s16x8*)&A[0][arow * ASTR + ks * 32 + kq];
            s16x8 a1 = *(const s16x8*)&A[1][arow * ASTR + ks * 32 + kq];
#pragma unroll
            for (int ci = 0; ci < 2; ++ci) {
                acc[ci][0] = __builtin_amdgcn_mfma_f32_16x16x32_bf16(
                    a0, Bf[ci][0][ks], acc[ci][0], 0, 0, 0);
                acc[ci][1] = __builtin_amdgcn_mfma_f32_16x16x32_bf16(
                    a1, Bf[ci][1][ks], acc[ci][1], 0, 0, 0);
            }
        }

#pragma unroll
        for (int ci = 0; ci < 2; ++ci) {
            int oc = (wv + ci * 4) * 16 + (lane & 15);
#pragma unroll
            for (int r = 0; r < 4; ++r) {
                int node = n0 + mt * 16 + quad * 4 + r;
                if (node < N_NODES) {
                    float v = lrelu(acc[ci][0][r] + bb1[ci])
                            + lrelu(acc[ci][1][r] + bb2[ci]);
                    out[(size_t)node * D + oc] = v;
                }
            }
        }
    }
}

// ============== Tier-0 fallback fp32 GEMM =====================================
__global__ __launch_bounds__(256) void gemm_kernel(
    const float* __restrict__ x, const float* __restrict__ h,
    const float* __restrict__ W1, const float* __restrict__ b1,
    const float* __restrict__ W2, const float* __restrict__ b2,
    float* __restrict__ out) {
    __shared__ float Aadd[32 * AP];
    __shared__ float Amul[32 * AP];
    const int n0 = blockIdx.x * 32;
    const int t = threadIdx.x;
#pragma unroll
    for (int i = 0; i < 4; ++i) {
        int fi = t + i * 256;
        int row = fi >> 5;
        int c4 = fi & 31;
        float4 xv = ((const float4*)(x + (size_t)(n0 + row) * D))[c4];
        float4 hv = ((const float4*)(h + (size_t)(n0 + row) * D))[c4];
        float4 av = make_float4(xv.x + hv.x, xv.y + hv.y, xv.z + hv.z, xv.w + hv.w);
        float4 mv = make_float4(xv.x * hv.x, xv.y * hv.y, xv.z * hv.z, xv.w * hv.w);
        *((float4*)&Aadd[row * AP + c4 * 4]) = av;
        *((float4*)&Amul[row * AP + c4 * 4]) = mv;
    }
    __syncthreads();
    const int m0 = (t >> 5) * 4;
    const int o0 = (t & 31) * 4;
    float acc1[4][4];
    float acc2[4][4];
#pragma unroll
    for (int i = 0; i < 4; ++i)
#pragma unroll
        for (int j = 0; j < 4; ++j) { acc1[i][j] = 0.0f; acc2[i][j] = 0.0f; }
#pragma unroll 4
    for (int d = 0; d < D; d += 4) {
        float4 a[4], m[4], w1[4], w2[4];
#pragma unroll
        for (int i = 0; i < 4; ++i) a[i] = *(const float4*)&Aadd[(m0 + i) * AP + d];
#pragma unroll
        for (int i = 0; i < 4; ++i) m[i] = *(const float4*)&Amul[(m0 + i) * AP + d];
#pragma unroll
        for (int j = 0; j < 4; ++j) w1[j] = *(const float4*)&W1[(size_t)(o0 + j) * D + d];
#pragma unroll
        for (int j = 0; j < 4; ++j) w2[j] = *(const float4*)&W2[(size_t)(o0 + j) * D + d];
#pragma unroll
        for (int i = 0; i < 4; ++i)
#pragma unroll
            for (int j = 0; j < 4; ++j) {
                acc1[i][j] += a[i].x * w1[j].x + a[i].y * w1[j].y
                            + a[i].z * w1[j].z + a[i].w * w1[j].w;
                acc2[i][j] += m[i].x * w2[j].x + m[i].y * w2[j].y
                            + m[i].z * w2[j].z + m[i].w * w2[j].w;
            }
    }
#pragma unroll
    for (int i = 0; i < 4; ++i) {
        float4 r;
        float v1, v2;
        v1 = lrelu(acc1[i][0] + b1[o0 + 0]); v2 = lrelu(acc2[i][0] + b2[o0 + 0]); r.x = v1 + v2;
        v1 = lrelu(acc1[i][1] + b1[o0 + 1]); v2 = lrelu(acc2[i][1] + b2[o0 + 1]); r.y = v1 + v2;
        v1 = lrelu(acc1[i][2] + b1[o0 + 2]); v2 = lrelu(acc2[i][2] + b2[o0 + 2]); r.z = v1 + v2;
        v1 = lrelu(acc1[i][3] + b1[o0 + 3]); v2 = lrelu(acc2[i][3] + b2[o0 + 3]); r.w = v1 + v2;
        ((float4*)(out + (size_t)(n0 + m0 + i) * D))[t & 31] = r;
    }
}

extern "C" void kernel_launch(void* const* d_in, const int* in_sizes, int n_in,
                              void* d_out, int out_size, void* d_ws, size_t ws_size,
                              hipStream_t stream) {
    const float* x   = (const float*)d_in[0];
    const int*   src = (const int*)d_in[1];
    const int*   dst = (const int*)d_in[2];
    const float* ea  = (const float*)d_in[3];
    const float* W1  = (const float*)d_in[4];
    const float* b1  = (const float*)d_in[5];
    const float* W2  = (const float*)d_in[6];
    const float* b2  = (const float*)d_in[7];
    float* out = (float*)d_out;

    // h aliases d_out: gather writes every row once; gemm blocks read their own
    // rows (into LDS, then __syncthreads) before overwriting those same rows.
    float* h = out;

    const size_t SZ_WSWZ = 2 * 4 * 8 * 64 * 8 * sizeof(unsigned short);     // 64 KB
    const size_t SZ_CNT  = (size_t)N_NODES * sizeof(int);                   // 400 KB
    const size_t SZ_OFF  = (size_t)(N_NODES + 1) * sizeof(int);
    const size_t SZ_BSUM = 512 * sizeof(int);
    const size_t SZ_RANK = (size_t)E_EDGES * sizeof(int);                   // 6.4 MB
    const size_t SZ_CSR  = (size_t)E_EDGES * sizeof(int2);                  // 12.8 MB
    const size_t SZ_XBF  = (size_t)N_NODES * D * sizeof(unsigned short);    // 25.6 MB
    auto align256 = [](size_t v) { return (v + 255) & ~(size_t)255; };
    size_t o_wswz = 0;
    size_t o_cnt  = o_wswz + align256(SZ_WSWZ);
    size_t o_off  = o_cnt + align256(SZ_CNT);
    size_t o_excl = o_off + align256(SZ_OFF);
    size_t o_bsum = o_excl + align256(SZ_CNT);
    size_t o_rank = o_bsum + align256(SZ_BSUM);
    size_t o_csr  = o_rank + align256(SZ_RANK);
    size_t o_xbf  = o_csr + align256(SZ_CSR);
    size_t need_t1 = o_xbf;                         // ~20.5 MB (no x_bf)
    size_t need_t2 = o_xbf + align256(SZ_XBF);      // ~46 MB

    const int NB_E = (E_EDGES + 255) / 256;
    const int NB_N = (N_NODES + 255) / 256;

    char* ws = (char*)d_ws;
    unsigned short* Wswz = (unsigned short*)(ws + o_wswz);
    int*   cnt  = (int*)(ws + o_cnt);
    int*   off  = (int*)(ws + o_off);
    int*   excl = (int*)(ws + o_excl);
    int*   bsum = (int*)(ws + o_bsum);
    int*   rank = (int*)(ws + o_rank);
    int2*  csr  = (int2*)(ws + o_csr);
    unsigned short* xbf = (unsigned short*)(ws + o_xbf);

    bool t2 = ws_size >= need_t2;
    bool t1 = ws_size >= need_t1;

    if (t1 || t2) {
        hipMemsetAsync(cnt, 0, SZ_CNT, stream);
        if (t2) xconv_kernel<<<(N_NODES * D / 8 + 255) / 256, 256, 0, stream>>>(x, xbf);
        hist_kernel<<<NB_E, 256, 0, stream>>>(dst, cnt, rank, E_EDGES);
        scanA_kernel<<<NB_N, 256, 0, stream>>>(cnt, excl, bsum, N_NODES);
        scanB_kernel<<<1, 512, 0, stream>>>(bsum, NB_N);
        scanC_kernel<<<NB_N, 256, 0, stream>>>(excl, bsum, off, N_NODES, E_EDGES);
        fill_kernel<<<NB_E, 256, 0, stream>>>(src, dst, ea, off, rank, csr, E_EDGES);
        if (t2)
            gather_bf_kernel<<<N_NODES / 4, 256, 0, stream>>>(xbf, csr, off, h);
        else
            gather_f32_kernel<<<N_NODES / 4, 256, 0, stream>>>(x, csr, off, h);

        wconv_kernel<<<16, 256, 0, stream>>>(W1, W2, Wswz);
        int blocks = (N_NODES + 63) / 64;
        if (t2)
            mfma_gemm_kernel<true><<<blocks, 256, 0, stream>>>(x, xbf, h, Wswz, b1, b2, out);
        else
            mfma_gemm_kernel<false><<<blocks, 256, 0, stream>>>(x, xbf, h, Wswz, b1, b2, out);
    } else {
        // Tier 0: atomic scatter + fp32 gemm (R1-proven)
        hipMemsetAsync(h, 0, (size_t)N_NODES * D * sizeof(float), stream);
        int total = E_EDGES * 32;
        scatter_kernel<<<(total + 255) / 256, 256, 0, stream>>>(x, src, dst, ea,
                                                                h, E_EDGES);
        gemm_kernel<<<N_NODES / 32, 256, 0, stream>>>(x, h, W1, b1, W2, b2, out);
    }
}